// Round 7
// baseline (735.018 us; speedup 1.0000x reference)
//
#include <hip/hip_runtime.h>
#include <cstdint>
#include <cstddef>

// GCN: 4x GCNConv (512->256->128->64->32) + mean-pool + 2-layer MLP.
// Round 7: barrier-free, LDS-free MFMA GEMM. Fragments loaded directly from
// global K-contiguous bf16 planes into registers, 2-deep manual double-buffer,
// K templated so the loop fully unrolls (addresses fold to base+imm).
// B (weights) is L2-resident; A re-reads are L3-served.

typedef __attribute__((ext_vector_type(8))) short s16x8;
typedef __attribute__((ext_vector_type(4))) float f32x4;

// fp32 -> (bf16 hi, bf16 lo) by truncation; lo captures the truncation error.
__device__ __forceinline__ short2 split2(float f) {
    union { float f; unsigned u; } c; c.f = f;
    short hi = (short)(c.u >> 16);
    union { unsigned u; float f; } h; h.u = c.u & 0xffff0000u;
    union { float f; unsigned u; } r; r.f = f - h.f;
    short lo = (short)(r.u >> 16);
    return make_short2(hi, lo);
}

// ---------------- x pre-split: [n][512] fp32 -> hi/lo planes [n][512] bf16 ----------------

__global__ void k_split_x(const float* __restrict__ x, long total8,
                          unsigned short* __restrict__ xh, unsigned short* __restrict__ xl) {
    long i = (long)blockIdx.x * blockDim.x + threadIdx.x;
    long stride = (long)gridDim.x * blockDim.x;
    for (; i < total8; i += stride) {
        const float4* p = (const float4*)(x + i * 8);
        float4 a = p[0], b = p[1];
        float v[8] = {a.x, a.y, a.z, a.w, b.x, b.y, b.z, b.w};
        s16x8 h, l;
#pragma unroll
        for (int j = 0; j < 8; ++j) { short2 q = split2(v[j]); h[j] = q.x; l[j] = q.y; }
        *(s16x8*)(xh + i * 8) = h;
        *(s16x8*)(xl + i * 8) = l;
    }
}

// ---------------- CSR build ----------------

__global__ void k_count(const int* __restrict__ dst, int E, int* __restrict__ cnt) {
    int e = blockIdx.x * blockDim.x + threadIdx.x;
    if (e < E) atomicAdd(&cnt[dst[e]], 1);
}

__global__ void k_dinv(const int* __restrict__ cnt, int n, float* __restrict__ dinv) {
    int i = blockIdx.x * blockDim.x + threadIdx.x;
    if (i < n) dinv[i] = rsqrtf((float)(cnt[i] + 1));
}

__global__ void k_scan_sums(const int* __restrict__ cnt, int n, int* __restrict__ bsum) {
    __shared__ int s[256];
    int t = threadIdx.x;
    int base = blockIdx.x * 4096 + t * 16;
    int sum = 0;
#pragma unroll
    for (int j = 0; j < 16; ++j) { int i = base + j; if (i < n) sum += cnt[i]; }
    s[t] = sum;
    __syncthreads();
    for (int off = 128; off > 0; off >>= 1) {
        if (t < off) s[t] += s[t + off];
        __syncthreads();
    }
    if (t == 0) bsum[blockIdx.x] = s[0];
}

__global__ void k_scan_offsets(const int* __restrict__ bsum, int nb,
                               int* __restrict__ boff, int* __restrict__ totalp) {
    int t = threadIdx.x;   // 64 threads
    int v = (t < nb) ? bsum[t] : 0;
    int x = v;
    for (int off = 1; off < 64; off <<= 1) {
        int y = __shfl_up(x, off);
        if (t >= off) x += y;
    }
    if (t < nb) boff[t] = x - v;
    if (t == 63) *totalp = x;
}

__global__ void k_scan_final(const int* __restrict__ cnt, int n,
                             const int* __restrict__ boff, int* __restrict__ row_ptr) {
    __shared__ int s[256];
    int t = threadIdx.x;
    int base = blockIdx.x * 4096 + t * 16;
    int v[16]; int sum = 0;
#pragma unroll
    for (int j = 0; j < 16; ++j) { int i = base + j; v[j] = (i < n) ? cnt[i] : 0; sum += v[j]; }
    s[t] = sum;
    __syncthreads();
    for (int off = 1; off < 256; off <<= 1) {
        int y = (t >= off) ? s[t - off] : 0;
        __syncthreads();
        s[t] += y;
        __syncthreads();
    }
    int run = boff[blockIdx.x] + ((t == 0) ? 0 : s[t - 1]);
#pragma unroll
    for (int j = 0; j < 16; ++j) {
        int i = base + j;
        if (i < n) row_ptr[i] = run;
        run += v[j];
    }
}

__global__ void k_fill(const int* __restrict__ src, const int* __restrict__ dst, int E,
                       const int* __restrict__ row_ptr, int* __restrict__ cursor,
                       int* __restrict__ csr_src) {
    int e = blockIdx.x * blockDim.x + threadIdx.x;
    if (e >= E) return;
    int d = dst[e];
    int p = atomicAdd(&cursor[d], 1);
    csr_src[row_ptr[d] + p] = src[e];
}

// ---------------- weight pre-split: w[K][N] fp32 -> Bt planes [N][K] bf16 ----------------

__global__ void k_split_w(const float* __restrict__ w, int N, int total, int kshift,
                          unsigned short* __restrict__ th, unsigned short* __restrict__ tl) {
    int idx = blockIdx.x * blockDim.x + threadIdx.x;
    if (idx >= total) return;
    int nn = idx >> kshift;
    int k  = idx & ((1 << kshift) - 1);
    short2 p = split2(w[(size_t)k * N + nn]);
    th[idx] = (unsigned short)p.x;
    tl[idx] = (unsigned short)p.y;
}

// ---------------- barrier-free, LDS-free split-bf16 MFMA GEMM ----------------
// C[M,N] = A[M,K]@B[K,N]. A planes [M][K], Bt planes [N][K] (both K-contig).
// 256 threads = 4 independent waves (2x2). Per wave: 64 x FN*16 output.
// Fragment loads: lane reads 16B at row/col (lane&15), k-slice (lane>>4)*8.
// 2-deep register double-buffer; K_ templated -> full unroll, imm offsets.

template <int FN, int K_>
__global__ __launch_bounds__(256)
void k_gemm(const unsigned short* __restrict__ Ah, const unsigned short* __restrict__ Al,
            const unsigned short* __restrict__ Bth, const unsigned short* __restrict__ Btl,
            float* __restrict__ C, int M, int N) {
    constexpr int FM = 4;
    constexpr int KT = K_ / 32;
    const int tid  = threadIdx.x;
    const int lane = tid & 63;
    const int w    = tid >> 6;
    const int wm   = w & 1;
    const int wn   = w >> 1;
    const int brow = blockIdx.y * 128;
    const int bcol = blockIdx.x * (FN * 32);
    const int l15  = lane & 15;
    const int ksl  = (lane >> 4) * 8;

    long aoff[FM], boff[FN];
#pragma unroll
    for (int i = 0; i < FM; ++i) {
        int row = brow + wm * 64 + i * 16 + l15;
        if (row > M - 1) row = M - 1;          // clamp: garbage rows only feed C rows >= M
        aoff[i] = (long)row * K_ + ksl;
    }
#pragma unroll
    for (int j = 0; j < FN; ++j) {
        int col = bcol + wn * FN * 16 + j * 16 + l15;
        boff[j] = (long)col * K_ + ksl;
    }

    f32x4 acc[FM][FN];
#pragma unroll
    for (int i = 0; i < FM; ++i)
#pragma unroll
        for (int j = 0; j < FN; ++j) acc[i][j] = (f32x4){0.f, 0.f, 0.f, 0.f};

    s16x8 a0h[FM], a0l[FM], a1h[FM], a1l[FM];
    s16x8 b0h[FN], b0l[FN], b1h[FN], b1l[FN];

    auto loadA = [&](s16x8 (&h)[FM], s16x8 (&l)[FM], int k0) {
#pragma unroll
        for (int i = 0; i < FM; ++i) {
            h[i] = *(const s16x8*)(Ah + aoff[i] + k0);
            l[i] = *(const s16x8*)(Al + aoff[i] + k0);
        }
    };
    auto loadB = [&](s16x8 (&h)[FN], s16x8 (&l)[FN], int k0) {
#pragma unroll
        for (int j = 0; j < FN; ++j) {
            h[j] = *(const s16x8*)(Bth + boff[j] + k0);
            l[j] = *(const s16x8*)(Btl + boff[j] + k0);
        }
    };
    auto stepM = [&](s16x8 (&ah)[FM], s16x8 (&al)[FM], s16x8 (&bh)[FN], s16x8 (&bl)[FN]) {
#pragma unroll
        for (int j = 0; j < FN; ++j)
#pragma unroll
            for (int i = 0; i < FM; ++i) {
                acc[i][j] = __builtin_amdgcn_mfma_f32_16x16x32_bf16(ah[i], bh[j], acc[i][j], 0, 0, 0);
                acc[i][j] = __builtin_amdgcn_mfma_f32_16x16x32_bf16(al[i], bh[j], acc[i][j], 0, 0, 0);
                acc[i][j] = __builtin_amdgcn_mfma_f32_16x16x32_bf16(ah[i], bl[j], acc[i][j], 0, 0, 0);
            }
    };

    // prologue: fill both buffers
    loadB(b0h, b0l, 0);
    loadA(a0h, a0l, 0);
    if (KT > 1) { loadB(b1h, b1l, 32); loadA(a1h, a1l, 32); }

#pragma unroll
    for (int t = 0; t < KT; t += 2) {
        stepM(a0h, a0l, b0h, b0l);
        if (t + 2 < KT) loadB(b0h, b0l, (t + 2) * 32);   // issue next-next B
        stepM(a1h, a1l, b1h, b1l);
        if (t + 2 < KT) {                                // refill set0/set1 a full iter ahead
            loadA(a0h, a0l, (t + 2) * 32);
            loadA(a1h, a1l, (t + 3) * 32);
            loadB(b1h, b1l, (t + 3) * 32);
        }
    }

    // C/D layout: col = lane&15, row = (lane>>4)*4 + reg
#pragma unroll
    for (int i = 0; i < FM; ++i) {
#pragma unroll
        for (int r = 0; r < 4; ++r) {
            int row = brow + wm * 64 + i * 16 + (lane >> 4) * 4 + r;
            if (row >= M) continue;
#pragma unroll
            for (int j = 0; j < FN; ++j) {
                int col = bcol + wn * FN * 16 + j * 16 + l15;
                C[(size_t)row * N + col] = acc[i][j][r];
            }
        }
    }
}

// ---------------- aggregation (+bias, relu) -> bf16 hi/lo planes ----------------

__global__ void k_agg_split(const float4* __restrict__ h, const int* __restrict__ row_ptr,
                            const int* __restrict__ csr_src, const float* __restrict__ dinv,
                            const float* __restrict__ bias,
                            unsigned short* __restrict__ oh, unsigned short* __restrict__ ol,
                            int n, int f_shift) {
    int idx = blockIdx.x * blockDim.x + threadIdx.x;
    int dout4 = 1 << f_shift;
    int total = n << f_shift;
    if (idx >= total) return;
    int i = idx >> f_shift;
    int f = idx & (dout4 - 1);

    float di = dinv[i];
    float4 hv = h[(size_t)i * dout4 + f];
    float4 acc;
    acc.x = hv.x * di; acc.y = hv.y * di; acc.z = hv.z * di; acc.w = hv.w * di;

    int s0 = row_ptr[i], s1 = row_ptr[i + 1];
    for (int e = s0; e < s1; ++e) {
        int s = csr_src[e];
        float ds = dinv[s];
        float4 v = h[(size_t)s * dout4 + f];
        acc.x += v.x * ds; acc.y += v.y * ds; acc.z += v.z * ds; acc.w += v.w * ds;
    }
    const float4* b4 = (const float4*)bias;
    float4 b = b4[f];
    float4 o;
    o.x = fmaxf(acc.x * di + b.x, 0.f);
    o.y = fmaxf(acc.y * di + b.y, 0.f);
    o.z = fmaxf(acc.z * di + b.z, 0.f);
    o.w = fmaxf(acc.w * di + b.w, 0.f);

    short2 p0 = split2(o.x), p1 = split2(o.y), p2 = split2(o.z), p3 = split2(o.w);
    size_t base = ((size_t)i << f_shift << 2) + f * 4;
    *(ushort4*)(oh + base) = make_ushort4((unsigned short)p0.x, (unsigned short)p1.x,
                                          (unsigned short)p2.x, (unsigned short)p3.x);
    *(ushort4*)(ol + base) = make_ushort4((unsigned short)p0.y, (unsigned short)p1.y,
                                          (unsigned short)p2.y, (unsigned short)p3.y);
}

// ---------------- aggregation (+bias), fp32 out (layer 4) ----------------

__global__ void k_agg(const float4* __restrict__ h, const int* __restrict__ row_ptr,
                      const int* __restrict__ csr_src, const float* __restrict__ dinv,
                      const float* __restrict__ bias, float4* __restrict__ out,
                      int n, int f_shift) {
    int idx = blockIdx.x * blockDim.x + threadIdx.x;
    int dout4 = 1 << f_shift;
    int total = n << f_shift;
    if (idx >= total) return;
    int i = idx >> f_shift;
    int f = idx & (dout4 - 1);

    float di = dinv[i];
    float4 hv = h[(size_t)i * dout4 + f];
    float4 acc;
    acc.x = hv.x * di; acc.y = hv.y * di; acc.z = hv.z * di; acc.w = hv.w * di;

    int s0 = row_ptr[i], s1 = row_ptr[i + 1];
    for (int e = s0; e < s1; ++e) {
        int s = csr_src[e];
        float ds = dinv[s];
        float4 v = h[(size_t)s * dout4 + f];
        acc.x += v.x * ds; acc.y += v.y * ds; acc.z += v.z * ds; acc.w += v.w * ds;
    }
    const float4* b4 = (const float4*)bias;
    float4 b = b4[f];
    float4 o;
    o.x = acc.x * di + b.x;
    o.y = acc.y * di + b.y;
    o.z = acc.z * di + b.z;
    o.w = acc.w * di + b.w;
    out[(size_t)i * dout4 + f] = o;
}

// ---------------- mean pool per graph (batch sorted) ----------------

__global__ void k_pool(const float* __restrict__ h, const int* __restrict__ batch,
                       int n, float* __restrict__ pooled) {
    int g = blockIdx.x;
    int start, end;
    {
        int lo = 0, hi = n;
        while (lo < hi) { int mid = (lo + hi) >> 1; if (batch[mid] < g) lo = mid + 1; else hi = mid; }
        start = lo;
        lo = start; hi = n;
        while (lo < hi) { int mid = (lo + hi) >> 1; if (batch[mid] < g + 1) lo = mid + 1; else hi = mid; }
        end = lo;
    }
    int f = threadIdx.x & 31;
    int sub = threadIdx.x >> 5;
    float s = 0.f;
    for (int i = start + sub; i < end; i += 8) s += h[(size_t)i * 32 + f];
    __shared__ float red[8][32];
    red[sub][f] = s;
    __syncthreads();
    if (sub == 0) {
        float t = 0.f;
#pragma unroll
        for (int k = 0; k < 8; ++k) t += red[k][f];
        int c = end - start;
        pooled[g * 32 + f] = t / (float)(c > 0 ? c : 1);
    }
}

// ---------------- tiny MLP head ----------------

__global__ void k_mlp(const float* __restrict__ pooled, const float* __restrict__ lw1,
                      const float* __restrict__ lb1, const float* __restrict__ lw2,
                      const float* __restrict__ lb2, float* __restrict__ out, int g_count) {
    int g = threadIdx.x;
    if (g >= g_count) return;
    float p[32];
#pragma unroll
    for (int k = 0; k < 32; ++k) p[k] = pooled[g * 32 + k];
    float hmid[16];
#pragma unroll
    for (int j = 0; j < 16; ++j) {
        float s = lb1[j];
#pragma unroll
        for (int k = 0; k < 32; ++k) s += p[k] * lw1[k * 16 + j];
        hmid[j] = fmaxf(s, 0.f);
    }
#pragma unroll
    for (int o = 0; o < 2; ++o) {
        float s = lb2[o];
#pragma unroll
        for (int k = 0; k < 16; ++k) s += hmid[k] * lw2[k * 2 + o];
        out[g * 2 + o] = s;
    }
}

// ---------------- launch ----------------

extern "C" void kernel_launch(void* const* d_in, const int* in_sizes, int n_in,
                              void* d_out, int out_size, void* d_ws, size_t ws_size,
                              hipStream_t stream) {
    const float* x     = (const float*)d_in[0];
    const int*   ei    = (const int*)d_in[1];
    const int*   batch = (const int*)d_in[2];
    const float* w1 = (const float*)d_in[3];  const float* b1 = (const float*)d_in[4];
    const float* w2 = (const float*)d_in[5];  const float* b2 = (const float*)d_in[6];
    const float* w3 = (const float*)d_in[7];  const float* b3 = (const float*)d_in[8];
    const float* w4 = (const float*)d_in[9];  const float* b4 = (const float*)d_in[10];
    const float* lw1 = (const float*)d_in[11]; const float* lb1 = (const float*)d_in[12];
    const float* lw2 = (const float*)d_in[13]; const float* lb2 = (const float*)d_in[14];
    float* out = (float*)d_out;

    const int n = in_sizes[0] / 512;   // 100000
    const int E = in_sizes[1] / 2;     // 320000
    const int G = 64;

    const int* src = ei;
    const int* dst = ei + E;

    char* ws = (char*)d_ws;
    size_t off = 0;
    auto alloc = [&](size_t bytes) -> void* {
        void* p = ws + off;
        off = (off + bytes + 255) & ~((size_t)255);
        return p;
    };
    float*          bufA = (float*)alloc((size_t)n * 256 * sizeof(float));  // GEMM out
    unsigned short* xh   = (unsigned short*)alloc((size_t)n * 512 * 2);     // x hi plane
    unsigned short* xl   = (unsigned short*)alloc((size_t)n * 512 * 2);     // x lo plane
    unsigned short* pAh  = (unsigned short*)alloc((size_t)n * 256 * 2);     // layer planes
    unsigned short* pAl  = (unsigned short*)alloc((size_t)n * 256 * 2);
    int*   cnt     = (int*)alloc((size_t)n * sizeof(int));
    int*   row_ptr = (int*)alloc((size_t)(n + 1) * sizeof(int));
    int*   cursor  = (int*)alloc((size_t)n * sizeof(int));
    int*   csr     = (int*)alloc((size_t)E * sizeof(int));
    float* dinv    = (float*)alloc((size_t)n * sizeof(float));
    float* pooled  = (float*)alloc((size_t)G * 32 * sizeof(float));
    int*   bsum    = (int*)alloc(64 * sizeof(int));
    int*   boff    = (int*)alloc(64 * sizeof(int));
    unsigned short* w1h = (unsigned short*)alloc(256 * 512 * 2);
    unsigned short* w1l = (unsigned short*)alloc(256 * 512 * 2);
    unsigned short* w2h = (unsigned short*)alloc(128 * 256 * 2);
    unsigned short* w2l = (unsigned short*)alloc(128 * 256 * 2);
    unsigned short* w3h = (unsigned short*)alloc(64 * 128 * 2);
    unsigned short* w3l = (unsigned short*)alloc(64 * 128 * 2);
    unsigned short* w4h = (unsigned short*)alloc(32 * 64 * 2);
    unsigned short* w4l = (unsigned short*)alloc(32 * 64 * 2);
    // layer-4 fp32 agg output parked in pAl beyond the live d=64 plane region
    float* bufB = (float*)(pAl + (size_t)n * 64);
    (void)ws_size;

    hipMemsetAsync(cnt, 0, (size_t)n * sizeof(int), stream);
    hipMemsetAsync(cursor, 0, (size_t)n * sizeof(int), stream);

    // pre-splits
    k_split_x<<<2048, 256, 0, stream>>>(x, (long)n * 64, xh, xl);
    k_split_w<<<(256 * 512 + 255) / 256, 256, 0, stream>>>(w1, 256, 256 * 512, 9, w1h, w1l);
    k_split_w<<<(128 * 256 + 255) / 256, 256, 0, stream>>>(w2, 128, 128 * 256, 8, w2h, w2l);
    k_split_w<<<(64 * 128 + 255) / 256, 256, 0, stream>>>(w3, 64, 64 * 128, 7, w3h, w3l);
    k_split_w<<<(32 * 64 + 255) / 256, 256, 0, stream>>>(w4, 32, 32 * 64, 6, w4h, w4l);

    const int nscan = (n + 4095) / 4096;
    k_count<<<(E + 255) / 256, 256, 0, stream>>>(dst, E, cnt);
    k_dinv <<<(n + 255) / 256, 256, 0, stream>>>(cnt, n, dinv);
    k_scan_sums   <<<nscan, 256, 0, stream>>>(cnt, n, bsum);
    k_scan_offsets<<<1, 64, 0, stream>>>(bsum, nscan, boff, row_ptr + n);
    k_scan_final  <<<nscan, 256, 0, stream>>>(cnt, n, boff, row_ptr);
    k_fill<<<(E + 255) / 256, 256, 0, stream>>>(src, dst, E, row_ptr, cursor, csr);

    const int gy = (n + 127) / 128;   // 782, BM=128

    // layer 1: [n,512]@[512,256], BN=128
    k_gemm<4, 512><<<dim3(2, gy), 256, 0, stream>>>(xh, xl, w1h, w1l, bufA, n, 256);
    k_agg_split<<<((size_t)n * 64 + 255) / 256, 256, 0, stream>>>(
        (const float4*)bufA, row_ptr, csr, dinv, b1, pAh, pAl, n, 6);

    // layer 2: [n,256]@[256,128], BN=128
    k_gemm<4, 256><<<dim3(1, gy), 256, 0, stream>>>(pAh, pAl, w2h, w2l, bufA, n, 128);
    k_agg_split<<<((size_t)n * 32 + 255) / 256, 256, 0, stream>>>(
        (const float4*)bufA, row_ptr, csr, dinv, b2, pAh, pAl, n, 5);

    // layer 3: [n,128]@[128,64], BN=64
    k_gemm<2, 128><<<dim3(1, gy), 256, 0, stream>>>(pAh, pAl, w3h, w3l, bufA, n, 64);
    k_agg_split<<<((size_t)n * 16 + 255) / 256, 256, 0, stream>>>(
        (const float4*)bufA, row_ptr, csr, dinv, b3, pAh, pAl, n, 4);

    // layer 4: [n,64]@[64,32], BN=32 (no relu)
    k_gemm<1, 64><<<dim3(1, gy), 256, 0, stream>>>(pAh, pAl, w4h, w4l, bufA, n, 32);
    k_agg<<<((size_t)n * 8 + 255) / 256, 256, 0, stream>>>(
        (const float4*)bufA, row_ptr, csr, dinv, b4, (float4*)bufB, n, 3);

    k_pool<<<G, 256, 0, stream>>>(bufB, batch, n, pooled);
    k_mlp<<<1, 64, 0, stream>>>(pooled, lw1, lb1, lw2, lb2, out, G);
}

// Round 8
// 498.741 us; speedup vs baseline: 1.4737x; 1.4737x over previous
//
#include <hip/hip_runtime.h>
#include <cstdint>
#include <cstddef>

// GCN: 4x GCNConv (512->256->128->64->32) + mean-pool + 2-layer MLP.
// Round 8: 2-phase double-buffered LDS GEMM (stage t+1 issued BEFORE MFMA t,
// one barrier per K-step). Layer 1 splits x fp32->bf16 hi/lo in-kernel
// (issue-early/write-late), deleting the separate split_x pass.

typedef __attribute__((ext_vector_type(8))) short s16x8;
typedef __attribute__((ext_vector_type(4))) float f32x4;

// fp32 -> (bf16 hi, bf16 lo) by truncation; lo captures the truncation error.
__device__ __forceinline__ short2 split2(float f) {
    union { float f; unsigned u; } c; c.f = f;
    short hi = (short)(c.u >> 16);
    union { unsigned u; float f; } h; h.u = c.u & 0xffff0000u;
    union { float f; unsigned u; } r; r.f = f - h.f;
    short lo = (short)(r.u >> 16);
    return make_short2(hi, lo);
}

// async 16B global -> LDS (wave-uniform LDS base; HW adds lane*16)
__device__ __forceinline__ void gload16(const void* g, void* l) {
    __builtin_amdgcn_global_load_lds(
        (const __attribute__((address_space(1))) unsigned int*)g,
        (__attribute__((address_space(3))) unsigned int*)l, 16, 0, 0);
}

// ---------------- CSR build ----------------

__global__ void k_count(const int* __restrict__ dst, int E, int* __restrict__ cnt) {
    int e = blockIdx.x * blockDim.x + threadIdx.x;
    if (e < E) atomicAdd(&cnt[dst[e]], 1);
}

__global__ void k_dinv(const int* __restrict__ cnt, int n, float* __restrict__ dinv) {
    int i = blockIdx.x * blockDim.x + threadIdx.x;
    if (i < n) dinv[i] = rsqrtf((float)(cnt[i] + 1));
}

__global__ void k_scan_sums(const int* __restrict__ cnt, int n, int* __restrict__ bsum) {
    __shared__ int s[256];
    int t = threadIdx.x;
    int base = blockIdx.x * 4096 + t * 16;
    int sum = 0;
#pragma unroll
    for (int j = 0; j < 16; ++j) { int i = base + j; if (i < n) sum += cnt[i]; }
    s[t] = sum;
    __syncthreads();
    for (int off = 128; off > 0; off >>= 1) {
        if (t < off) s[t] += s[t + off];
        __syncthreads();
    }
    if (t == 0) bsum[blockIdx.x] = s[0];
}

__global__ void k_scan_offsets(const int* __restrict__ bsum, int nb,
                               int* __restrict__ boff, int* __restrict__ totalp) {
    int t = threadIdx.x;   // 64 threads
    int v = (t < nb) ? bsum[t] : 0;
    int x = v;
    for (int off = 1; off < 64; off <<= 1) {
        int y = __shfl_up(x, off);
        if (t >= off) x += y;
    }
    if (t < nb) boff[t] = x - v;
    if (t == 63) *totalp = x;
}

__global__ void k_scan_final(const int* __restrict__ cnt, int n,
                             const int* __restrict__ boff, int* __restrict__ row_ptr) {
    __shared__ int s[256];
    int t = threadIdx.x;
    int base = blockIdx.x * 4096 + t * 16;
    int v[16]; int sum = 0;
#pragma unroll
    for (int j = 0; j < 16; ++j) { int i = base + j; v[j] = (i < n) ? cnt[i] : 0; sum += v[j]; }
    s[t] = sum;
    __syncthreads();
    for (int off = 1; off < 256; off <<= 1) {
        int y = (t >= off) ? s[t - off] : 0;
        __syncthreads();
        s[t] += y;
        __syncthreads();
    }
    int run = boff[blockIdx.x] + ((t == 0) ? 0 : s[t - 1]);
#pragma unroll
    for (int j = 0; j < 16; ++j) {
        int i = base + j;
        if (i < n) row_ptr[i] = run;
        run += v[j];
    }
}

__global__ void k_fill(const int* __restrict__ src, const int* __restrict__ dst, int E,
                       const int* __restrict__ row_ptr, int* __restrict__ cursor,
                       int* __restrict__ csr_src) {
    int e = blockIdx.x * blockDim.x + threadIdx.x;
    if (e >= E) return;
    int d = dst[e];
    int p = atomicAdd(&cursor[d], 1);
    csr_src[row_ptr[d] + p] = src[e];
}

// ---------------- weight pre-split: w[K][N] fp32 -> Bt planes [N][K] bf16 ----------------

__global__ void k_split_w(const float* __restrict__ w, int N, int total, int kshift,
                          unsigned short* __restrict__ th, unsigned short* __restrict__ tl) {
    int idx = blockIdx.x * blockDim.x + threadIdx.x;
    if (idx >= total) return;
    int nn = idx >> kshift;
    int k  = idx & ((1 << kshift) - 1);
    short2 p = split2(w[(size_t)k * N + nn]);
    th[idx] = (unsigned short)p.x;
    tl[idx] = (unsigned short)p.y;
}

// ---------------- 2-phase dbuf split-bf16 MFMA GEMM ----------------
// C[M,N] = A[M,K]@B[K,N]. 256 threads, 4 waves (2x2), BM=128, BN=FN*32, BK=32.
// Double-buffered LDS; stage of tile t+1 is issued BEFORE ds_read+MFMA of
// tile t; ONE __syncthreads per K-step (drain happens after a full MFMA
// phase of load flight time). Layer 1 (SPLIT_A): A staged via
// global->reg (issued early) -> split -> ds_write (late, after MFMA).
// LDS chunk swizzle: 16B-chunk-in-row q stored at q ^ ((row>>1)&3).

template <int FN, bool SPLIT_A>
__global__ __launch_bounds__(256)
void k_gemm(const float* __restrict__ A32,
            const unsigned short* __restrict__ Ah, const unsigned short* __restrict__ Al,
            const unsigned short* __restrict__ Bth, const unsigned short* __restrict__ Btl,
            float* __restrict__ C, int M, int K, int N) {
    constexpr int FM = 4;
    constexpr int BM = 128;
    constexpr int BN = FN * 32;
    constexpr int ABYTES = BM * 64;               // one A plane
    constexpr int BBYTES = BN * 64;               // one B plane
    constexpr int BUF = 2 * ABYTES + 2 * BBYTES;  // hi+lo, A+B
    __shared__ char lds[2 * BUF];

    const int tid  = threadIdx.x;
    const int lane = tid & 63;
    const int w    = tid >> 6;
    const int wm   = w & 1;
    const int wn   = w >> 1;
    const int brow = blockIdx.y * BM;
    const int bcol = blockIdx.x * BN;
    const int l15  = lane & 15;
    const int kb   = (lane >> 4) * 16;

    // SPLIT_A reg-staging geometry: thread -> (row = tid>>1, k-half = tid&1)
    const int arow_t = tid >> 1;
    const int ahalf  = tid & 1;
    int arow_g = brow + arow_t; if (arow_g > M - 1) arow_g = M - 1;   // clamp (safe dup)
    const float* xrow = A32 + (size_t)arow_g * K + ahalf * 16;

    f32x4 acc[FM][FN];
#pragma unroll
    for (int i = 0; i < FM; ++i)
#pragma unroll
        for (int j = 0; j < FN; ++j) acc[i][j] = (f32x4){0.f, 0.f, 0.f, 0.f};

    const int KT = K / 32;
    float4 xr0, xr1, xr2, xr3;

    auto loadX = [&](int k0) {
        const float4* p = (const float4*)(xrow + k0);
        xr0 = p[0]; xr1 = p[1]; xr2 = p[2]; xr3 = p[3];
    };
    auto writeA = [&](char* base) {
        float v[16] = {xr0.x, xr0.y, xr0.z, xr0.w, xr1.x, xr1.y, xr1.z, xr1.w,
                       xr2.x, xr2.y, xr2.z, xr2.w, xr3.x, xr3.y, xr3.z, xr3.w};
        s16x8 h0, h1, l0, l1;
#pragma unroll
        for (int j = 0; j < 8; ++j) { short2 q = split2(v[j]);     h0[j] = q.x; l0[j] = q.y; }
#pragma unroll
        for (int j = 0; j < 8; ++j) { short2 q = split2(v[8 + j]); h1[j] = q.x; l1[j] = q.y; }
        int vq = (arow_t >> 1) & 3;
        int q0 = (2 * ahalf) ^ vq;
        int q1 = (2 * ahalf + 1) ^ vq;
        char* sAh = base;
        char* sAl = base + ABYTES;
        *(s16x8*)(sAh + arow_t * 64 + q0 * 16) = h0;
        *(s16x8*)(sAh + arow_t * 64 + q1 * 16) = h1;
        *(s16x8*)(sAl + arow_t * 64 + q0 * 16) = l0;
        *(s16x8*)(sAl + arow_t * 64 + q1 * 16) = l1;
    };
    auto stageAg = [&](char* base, int k0) {   // !SPLIT_A: async copy from planes
#pragma unroll
        for (int u = 0; u < 4; ++u) {
            int id = w + u * 4;                 // 0..15
            int hi = (id < 8) ? 1 : 0;
            int s  = hi ? id : id - 8;
            int p  = s * 64 + lane;
            int kq = (p ^ ((p >> 3) & 3)) & 3;
            int row = p >> 2;
            const unsigned short* gs = (hi ? Ah : Al) + (size_t)(brow + row) * K + k0 + kq * 8;
            gload16(gs, base + (hi ? 0 : ABYTES) + s * 1024);
        }
    };
    auto stageB = [&](char* base, int k0) {
        char* sBh = base + 2 * ABYTES;
        char* sBl = sBh + BBYTES;
#pragma unroll
        for (int u = 0; u < BN / 32; ++u) {
            int id = w + u * 4;                 // 0 .. BN/8-1
            int hi = (id < BN / 16) ? 1 : 0;
            int s  = hi ? id : id - BN / 16;
            int p  = s * 64 + lane;
            int kq = (p ^ ((p >> 3) & 3)) & 3;
            int col = p >> 2;
            const unsigned short* gs = (hi ? Bth : Btl) + (size_t)(bcol + col) * K + k0 + kq * 8;
            gload16(gs, (hi ? sBh : sBl) + s * 1024);
        }
    };

    // ---- prologue: fill buffer 0 for t=0 ----
    char* cur = lds;
    char* nxt = lds + BUF;
    if constexpr (SPLIT_A) loadX(0);
    stageB(cur, 0);
    if constexpr (SPLIT_A) writeA(cur); else stageAg(cur, 0);
    __syncthreads();

    for (int t = 0; t < KT; ++t) {
        const int k1 = (t + 1) * 32;
        const bool more = (t + 1 < KT);
        if (more) {                      // issue next tile's loads FIRST
            if constexpr (SPLIT_A) loadX(k1);
            stageB(nxt, k1);
            if constexpr (!SPLIT_A) stageAg(nxt, k1);
        }

        // ---- fragments + MFMA from cur ----
        {
            char* sAh = cur;
            char* sAl = cur + ABYTES;
            char* sBh = cur + 2 * ABYTES;
            char* sBl = sBh + BBYTES;
            s16x8 fah[FM], fam[FM];
#pragma unroll
            for (int i = 0; i < FM; ++i) {
                int row = wm * 64 + i * 16 + l15;
                int o = row * 64 + (kb ^ (((row >> 1) & 3) << 4));
                fah[i] = *(const s16x8*)(sAh + o);
                fam[i] = *(const s16x8*)(sAl + o);
            }
#pragma unroll
            for (int j = 0; j < FN; ++j) {
                int col = wn * FN * 16 + j * 16 + l15;
                int o = col * 64 + (kb ^ (((col >> 1) & 3) << 4));
                s16x8 fbh = *(const s16x8*)(sBh + o);
                s16x8 fbm = *(const s16x8*)(sBl + o);
#pragma unroll
                for (int i = 0; i < FM; ++i) {
                    acc[i][j] = __builtin_amdgcn_mfma_f32_16x16x32_bf16(fah[i], fbh, acc[i][j], 0, 0, 0);
                    acc[i][j] = __builtin_amdgcn_mfma_f32_16x16x32_bf16(fam[i], fbh, acc[i][j], 0, 0, 0);
                    acc[i][j] = __builtin_amdgcn_mfma_f32_16x16x32_bf16(fah[i], fbm, acc[i][j], 0, 0, 0);
                }
            }
        }

        if constexpr (SPLIT_A) {
            if (more) writeA(nxt);       // late write: x loads had the MFMA phase
        }
        __syncthreads();                 // one drain per K-step
        char* tmp = cur; cur = nxt; nxt = tmp;
    }

    // C/D layout: col = lane&15, row = (lane>>4)*4 + reg
#pragma unroll
    for (int i = 0; i < FM; ++i) {
#pragma unroll
        for (int r = 0; r < 4; ++r) {
            int row = brow + wm * 64 + i * 16 + (lane >> 4) * 4 + r;
            if (row >= M) continue;
#pragma unroll
            for (int j = 0; j < FN; ++j) {
                int col = bcol + wn * FN * 16 + j * 16 + l15;
                C[(size_t)row * N + col] = acc[i][j][r];
            }
        }
    }
}

// ---------------- aggregation (+bias, relu) -> bf16 hi/lo planes ----------------

__global__ void k_agg_split(const float4* __restrict__ h, const int* __restrict__ row_ptr,
                            const int* __restrict__ csr_src, const float* __restrict__ dinv,
                            const float* __restrict__ bias,
                            unsigned short* __restrict__ oh, unsigned short* __restrict__ ol,
                            int n, int f_shift) {
    int idx = blockIdx.x * blockDim.x + threadIdx.x;
    int dout4 = 1 << f_shift;
    int total = n << f_shift;
    if (idx >= total) return;
    int i = idx >> f_shift;
    int f = idx & (dout4 - 1);

    float di = dinv[i];
    float4 hv = h[(size_t)i * dout4 + f];
    float4 acc;
    acc.x = hv.x * di; acc.y = hv.y * di; acc.z = hv.z * di; acc.w = hv.w * di;

    int s0 = row_ptr[i], s1 = row_ptr[i + 1];
    for (int e = s0; e < s1; ++e) {
        int s = csr_src[e];
        float ds = dinv[s];
        float4 v = h[(size_t)s * dout4 + f];
        acc.x += v.x * ds; acc.y += v.y * ds; acc.z += v.z * ds; acc.w += v.w * ds;
    }
    const float4* b4 = (const float4*)bias;
    float4 b = b4[f];
    float4 o;
    o.x = fmaxf(acc.x * di + b.x, 0.f);
    o.y = fmaxf(acc.y * di + b.y, 0.f);
    o.z = fmaxf(acc.z * di + b.z, 0.f);
    o.w = fmaxf(acc.w * di + b.w, 0.f);

    short2 p0 = split2(o.x), p1 = split2(o.y), p2 = split2(o.z), p3 = split2(o.w);
    size_t base = ((size_t)i << f_shift << 2) + f * 4;
    *(ushort4*)(oh + base) = make_ushort4((unsigned short)p0.x, (unsigned short)p1.x,
                                          (unsigned short)p2.x, (unsigned short)p3.x);
    *(ushort4*)(ol + base) = make_ushort4((unsigned short)p0.y, (unsigned short)p1.y,
                                          (unsigned short)p2.y, (unsigned short)p3.y);
}

// ---------------- aggregation (+bias), fp32 out (layer 4) ----------------

__global__ void k_agg(const float4* __restrict__ h, const int* __restrict__ row_ptr,
                      const int* __restrict__ csr_src, const float* __restrict__ dinv,
                      const float* __restrict__ bias, float4* __restrict__ out,
                      int n, int f_shift) {
    int idx = blockIdx.x * blockDim.x + threadIdx.x;
    int dout4 = 1 << f_shift;
    int total = n << f_shift;
    if (idx >= total) return;
    int i = idx >> f_shift;
    int f = idx & (dout4 - 1);

    float di = dinv[i];
    float4 hv = h[(size_t)i * dout4 + f];
    float4 acc;
    acc.x = hv.x * di; acc.y = hv.y * di; acc.z = hv.z * di; acc.w = hv.w * di;

    int s0 = row_ptr[i], s1 = row_ptr[i + 1];
    for (int e = s0; e < s1; ++e) {
        int s = csr_src[e];
        float ds = dinv[s];
        float4 v = h[(size_t)s * dout4 + f];
        acc.x += v.x * ds; acc.y += v.y * ds; acc.z += v.z * ds; acc.w += v.w * ds;
    }
    const float4* b4 = (const float4*)bias;
    float4 b = b4[f];
    float4 o;
    o.x = acc.x * di + b.x;
    o.y = acc.y * di + b.y;
    o.z = acc.z * di + b.z;
    o.w = acc.w * di + b.w;
    out[(size_t)i * dout4 + f] = o;
}

// ---------------- mean pool per graph (batch sorted) ----------------

__global__ void k_pool(const float* __restrict__ h, const int* __restrict__ batch,
                       int n, float* __restrict__ pooled) {
    int g = blockIdx.x;
    int start, end;
    {
        int lo = 0, hi = n;
        while (lo < hi) { int mid = (lo + hi) >> 1; if (batch[mid] < g) lo = mid + 1; else hi = mid; }
        start = lo;
        lo = start; hi = n;
        while (lo < hi) { int mid = (lo + hi) >> 1; if (batch[mid] < g + 1) lo = mid + 1; else hi = mid; }
        end = lo;
    }
    int f = threadIdx.x & 31;
    int sub = threadIdx.x >> 5;
    float s = 0.f;
    for (int i = start + sub; i < end; i += 8) s += h[(size_t)i * 32 + f];
    __shared__ float red[8][32];
    red[sub][f] = s;
    __syncthreads();
    if (sub == 0) {
        float t = 0.f;
#pragma unroll
        for (int k = 0; k < 8; ++k) t += red[k][f];
        int c = end - start;
        pooled[g * 32 + f] = t / (float)(c > 0 ? c : 1);
    }
}

// ---------------- tiny MLP head ----------------

__global__ void k_mlp(const float* __restrict__ pooled, const float* __restrict__ lw1,
                      const float* __restrict__ lb1, const float* __restrict__ lw2,
                      const float* __restrict__ lb2, float* __restrict__ out, int g_count) {
    int g = threadIdx.x;
    if (g >= g_count) return;
    float p[32];
#pragma unroll
    for (int k = 0; k < 32; ++k) p[k] = pooled[g * 32 + k];
    float hmid[16];
#pragma unroll
    for (int j = 0; j < 16; ++j) {
        float s = lb1[j];
#pragma unroll
        for (int k = 0; k < 32; ++k) s += p[k] * lw1[k * 16 + j];
        hmid[j] = fmaxf(s, 0.f);
    }
#pragma unroll
    for (int o = 0; o < 2; ++o) {
        float s = lb2[o];
#pragma unroll
        for (int k = 0; k < 16; ++k) s += hmid[k] * lw2[k * 2 + o];
        out[g * 2 + o] = s;
    }
}

// ---------------- launch ----------------

extern "C" void kernel_launch(void* const* d_in, const int* in_sizes, int n_in,
                              void* d_out, int out_size, void* d_ws, size_t ws_size,
                              hipStream_t stream) {
    const float* x     = (const float*)d_in[0];
    const int*   ei    = (const int*)d_in[1];
    const int*   batch = (const int*)d_in[2];
    const float* w1 = (const float*)d_in[3];  const float* b1 = (const float*)d_in[4];
    const float* w2 = (const float*)d_in[5];  const float* b2 = (const float*)d_in[6];
    const float* w3 = (const float*)d_in[7];  const float* b3 = (const float*)d_in[8];
    const float* w4 = (const float*)d_in[9];  const float* b4 = (const float*)d_in[10];
    const float* lw1 = (const float*)d_in[11]; const float* lb1 = (const float*)d_in[12];
    const float* lw2 = (const float*)d_in[13]; const float* lb2 = (const float*)d_in[14];
    float* out = (float*)d_out;

    const int n = in_sizes[0] / 512;   // 100000
    const int E = in_sizes[1] / 2;     // 320000
    const int G = 64;

    const int* src = ei;
    const int* dst = ei + E;

    char* ws = (char*)d_ws;
    size_t off = 0;
    auto alloc = [&](size_t bytes) -> void* {
        void* p = ws + off;
        off = (off + bytes + 255) & ~((size_t)255);
        return p;
    };
    float*          bufA = (float*)alloc((size_t)n * 256 * sizeof(float));  // GEMM out
    unsigned short* pAh  = (unsigned short*)alloc((size_t)n * 256 * 2);     // layer planes
    unsigned short* pAl  = (unsigned short*)alloc((size_t)n * 256 * 2);
    int*   cnt     = (int*)alloc((size_t)n * sizeof(int));
    int*   row_ptr = (int*)alloc((size_t)(n + 1) * sizeof(int));
    int*   cursor  = (int*)alloc((size_t)n * sizeof(int));
    int*   csr     = (int*)alloc((size_t)E * sizeof(int));
    float* dinv    = (float*)alloc((size_t)n * sizeof(float));
    float* pooled  = (float*)alloc((size_t)G * 32 * sizeof(float));
    int*   bsum    = (int*)alloc(64 * sizeof(int));
    int*   boff    = (int*)alloc(64 * sizeof(int));
    unsigned short* w1h = (unsigned short*)alloc(256 * 512 * 2);
    unsigned short* w1l = (unsigned short*)alloc(256 * 512 * 2);
    unsigned short* w2h = (unsigned short*)alloc(128 * 256 * 2);
    unsigned short* w2l = (unsigned short*)alloc(128 * 256 * 2);
    unsigned short* w3h = (unsigned short*)alloc(64 * 128 * 2);
    unsigned short* w3l = (unsigned short*)alloc(64 * 128 * 2);
    unsigned short* w4h = (unsigned short*)alloc(32 * 64 * 2);
    unsigned short* w4l = (unsigned short*)alloc(32 * 64 * 2);
    // layer-4 fp32 agg output parked in pAl beyond the live d=64 plane region
    float* bufB = (float*)(pAl + (size_t)n * 64);
    (void)ws_size;

    hipMemsetAsync(cnt, 0, (size_t)n * sizeof(int), stream);
    hipMemsetAsync(cursor, 0, (size_t)n * sizeof(int), stream);

    // weight pre-split (tiny)
    k_split_w<<<(256 * 512 + 255) / 256, 256, 0, stream>>>(w1, 256, 256 * 512, 9, w1h, w1l);
    k_split_w<<<(128 * 256 + 255) / 256, 256, 0, stream>>>(w2, 128, 128 * 256, 8, w2h, w2l);
    k_split_w<<<(64 * 128 + 255) / 256, 256, 0, stream>>>(w3, 64, 64 * 128, 7, w3h, w3l);
    k_split_w<<<(32 * 64 + 255) / 256, 256, 0, stream>>>(w4, 32, 32 * 64, 6, w4h, w4l);

    const int nscan = (n + 4095) / 4096;
    k_count<<<(E + 255) / 256, 256, 0, stream>>>(dst, E, cnt);
    k_dinv <<<(n + 255) / 256, 256, 0, stream>>>(cnt, n, dinv);
    k_scan_sums   <<<nscan, 256, 0, stream>>>(cnt, n, bsum);
    k_scan_offsets<<<1, 64, 0, stream>>>(bsum, nscan, boff, row_ptr + n);
    k_scan_final  <<<nscan, 256, 0, stream>>>(cnt, n, boff, row_ptr);
    k_fill<<<(E + 255) / 256, 256, 0, stream>>>(src, dst, E, row_ptr, cursor, csr);

    const int gy = (n + 127) / 128;   // 782, BM=128

    // layer 1: [n,512]@[512,256], BN=128, x split in-kernel
    k_gemm<4, true><<<dim3(2, gy), 256, 0, stream>>>(
        x, nullptr, nullptr, w1h, w1l, bufA, n, 512, 256);
    k_agg_split<<<((size_t)n * 64 + 255) / 256, 256, 0, stream>>>(
        (const float4*)bufA, row_ptr, csr, dinv, b1, pAh, pAl, n, 6);

    // layer 2: [n,256]@[256,128]
    k_gemm<4, false><<<dim3(1, gy), 256, 0, stream>>>(
        nullptr, pAh, pAl, w2h, w2l, bufA, n, 256, 128);
    k_agg_split<<<((size_t)n * 32 + 255) / 256, 256, 0, stream>>>(
        (const float4*)bufA, row_ptr, csr, dinv, b2, pAh, pAl, n, 5);

    // layer 3: [n,128]@[128,64]
    k_gemm<2, false><<<dim3(1, gy), 256, 0, stream>>>(
        nullptr, pAh, pAl, w3h, w3l, bufA, n, 128, 64);
    k_agg_split<<<((size_t)n * 16 + 255) / 256, 256, 0, stream>>>(
        (const float4*)bufA, row_ptr, csr, dinv, b3, pAh, pAl, n, 4);

    // layer 4: [n,64]@[64,32] (no relu)
    k_gemm<1, false><<<dim3(1, gy), 256, 0, stream>>>(
        nullptr, pAh, pAl, w4h, w4l, bufA, n, 64, 32);
    k_agg<<<((size_t)n * 8 + 255) / 256, 256, 0, stream>>>(
        (const float4*)bufA, row_ptr, csr, dinv, b4, (float4*)bufB, n, 3);

    k_pool<<<G, 256, 0, stream>>>(bufB, batch, n, pooled);
    k_mlp<<<1, 64, 0, stream>>>(pooled, lw1, lb1, lw2, lb2, out, G);
}